// Round 5
// baseline (136.622 us; speedup 1.0000x reference)
//
#include <hip/hip_runtime.h>

#define B_ 32
#define HH 56
#define WW 56
#define C_ 96
#define E_ 4
#define M_ 384
#define F_ 96
#define P_ 3136
#define EPS 1e-3f

typedef __attribute__((ext_vector_type(8))) __bf16 bf16x8;
typedef __attribute__((ext_vector_type(8))) short short8;
typedef __attribute__((ext_vector_type(4))) float f32x4;
typedef __attribute__((ext_vector_type(2))) float f32x2;
typedef __attribute__((ext_vector_type(4))) unsigned short us4;
typedef unsigned short u16;

__device__ __forceinline__ float bf2f(u16 s) {
  union { unsigned u; float f; } c;
  c.u = ((unsigned)s) << 16;
  return c.f;
}
__device__ __forceinline__ u16 f2bf(float f) {
  union { float f; unsigned u; } c;
  c.f = f;
  unsigned u = c.u + 0x7FFFu + ((c.u >> 16) & 1u);
  return (u16)(u >> 16);
}
__device__ __forceinline__ f32x2 bfpair(unsigned u) {
  union { unsigned i; float f; } lo, hi;
  lo.i = u << 16;
  hi.i = u & 0xffff0000u;
  f32x2 r;
  r.x = lo.f;
  r.y = hi.f;
  return r;
}

// ---------------- x -> bf16 + per-chunk partial channel sums
__global__ __launch_bounds__(256) void k_pool_convert(
    const float* __restrict__ x, float* __restrict__ partial, u16* __restrict__ xbf) {
  int chunk = blockIdx.x, b = blockIdx.y;
  int p0 = chunk * 49;
  const float* xb = x + ((size_t)b * P_ + p0) * C_;
  u16* xo = xbf + ((size_t)b * P_ + p0) * C_;
  int t = threadIdx.x;
  int c4 = t % 24, s = t / 24;
  __shared__ f32x4 part[10][24];
  if (s < 10) {
    f32x4 sum = {0.f, 0.f, 0.f, 0.f};
    for (int p = s; p < 49; p += 10) {
      f32x4 v = *(const f32x4*)&xb[(size_t)p * C_ + c4 * 4];
      sum += v;
      us4 o;
      o.x = f2bf(v.x); o.y = f2bf(v.y); o.z = f2bf(v.z); o.w = f2bf(v.w);
      *(us4*)&xo[(size_t)p * C_ + c4 * 4] = o;
    }
    part[s][c4] = sum;
  }
  __syncthreads();
  if (s == 0) {
    f32x4 acc = part[0][c4];
#pragma unroll
    for (int ss = 1; ss < 10; ++ss) acc += part[ss][c4];
    *(f32x4*)&partial[(((size_t)b * 64 + chunk)) * C_ + c4 * 4] = acc;
  }
}

// ---------------- finish pooling + dense + sigmoid
__global__ __launch_bounds__(128) void k_routing2(
    const float* __restrict__ partial, const float* __restrict__ Wr,
    const float* __restrict__ br, float* __restrict__ rw) {
  int b = blockIdx.x;
  int c = threadIdx.x;
  __shared__ float pooled[C_];
  if (c < C_) {
    float s = 0.f;
    for (int ch = 0; ch < 64; ++ch) s += partial[((size_t)b * 64 + ch) * C_ + c];
    pooled[c] = s * (1.f / (float)P_);
  }
  __syncthreads();
  if (c < E_) {
    float acc = br[c];
    for (int cc = 0; cc < C_; ++cc) acc += pooled[cc] * Wr[cc * E_ + c];
    rw[b * E_ + c] = 1.f / (1.f + expf(-acc));
  }
}

// ---------------- all weight combines in one kernel. grid (B_, 13), 256 thr
__global__ __launch_bounds__(256) void k_mkall(
    const float* __restrict__ Wpw, const float* __restrict__ bpw,
    const float* __restrict__ Wdw, const float* __restrict__ bdw,
    const float* __restrict__ Wpwl, const float* __restrict__ bpwl,
    const float* __restrict__ rw,
    const float* __restrict__ g1, const float* __restrict__ b1,
    const float* __restrict__ m1, const float* __restrict__ v1,
    const float* __restrict__ g2, const float* __restrict__ b2,
    const float* __restrict__ m2, const float* __restrict__ v2,
    const float* __restrict__ g3, const float* __restrict__ b3,
    const float* __restrict__ m3, const float* __restrict__ v3,
    u16* __restrict__ Wk_t, float* __restrict__ bias1p,
    float* __restrict__ Wdwf_t,
    u16* __restrict__ Wk2_t, float* __restrict__ bias3p) {
  int b = blockIdx.x, seg = blockIdx.y;
  float r0 = rw[b * 4 + 0], r1 = rw[b * 4 + 1], r2 = rw[b * 4 + 2], r3 = rw[b * 4 + 3];
  int t = threadIdx.x;
  if (seg < 6) {
    __shared__ __align__(16) u16 tile[64][104];
    int ml = t & 63;
    int m = seg * 64 + ml, cp = t >> 6;
    float s1 = g1[m] * rsqrtf(v1[m] + EPS);
#pragma unroll
    for (int j = 0; j < 24; ++j) {
      int c = cp + 4 * j;
      float w = r0 * Wpw[(0 * C_ + c) * M_ + m] + r1 * Wpw[(1 * C_ + c) * M_ + m] +
                r2 * Wpw[(2 * C_ + c) * M_ + m] + r3 * Wpw[(3 * C_ + c) * M_ + m];
      tile[ml][c] = f2bf(w * s1);
    }
    __syncthreads();
    u16* dst = Wk_t + ((size_t)b * M_ + seg * 64) * C_;
#pragma unroll
    for (int k = 0; k < 3; ++k) {
      int ch = t + 256 * k;
      int mr = ch / 12, off = (ch % 12) * 8;
      *(short8*)&dst[(size_t)mr * C_ + off] = *(const short8*)&tile[mr][off];
    }
  } else if (seg == 6) {
    for (int m = t; m < M_; m += 256) {
      float s2 = g2[m] * rsqrtf(v2[m] + EPS);
      int oct = m >> 3, q = m & 7;
      float* base = Wdwf_t + ((size_t)b * 48 + oct) * 80;
#pragma unroll
      for (int tap = 0; tap < 9; ++tap) {
        float w = r0 * Wdw[(0 * 9 + tap) * M_ + m] + r1 * Wdw[(1 * 9 + tap) * M_ + m] +
                  r2 * Wdw[(2 * 9 + tap) * M_ + m] + r3 * Wdw[(3 * 9 + tap) * M_ + m];
        base[tap * 8 + q] = w * s2;
      }
      float bias = r0 * bdw[m] + r1 * bdw[M_ + m] + r2 * bdw[2 * M_ + m] + r3 * bdw[3 * M_ + m];
      base[72 + q] = (bias - m2[m]) * s2 + b2[m];
      float s1 = g1[m] * rsqrtf(v1[m] + EPS);
      float bb = r0 * bpw[m] + r1 * bpw[M_ + m] + r2 * bpw[2 * M_ + m] + r3 * bpw[3 * M_ + m];
      bias1p[b * M_ + m] = (bb - m1[m]) * s1 + b1[m];
    }
    if (t < F_) {
      float s3 = g3[t] * rsqrtf(v3[t] + EPS);
      float bb = r0 * bpwl[t] + r1 * bpwl[F_ + t] + r2 * bpwl[2 * F_ + t] + r3 * bpwl[3 * F_ + t];
      bias3p[b * F_ + t] = (bb - m3[t]) * s3 + b3[t];
    }
  } else {
    __shared__ __align__(16) u16 tile2[96][72];
    int m0 = (seg - 7) * 64;
#pragma unroll
    for (int j = 0; j < 24; ++j) {
      int id = t + 256 * j;
      int m = id / 96, f = id % 96;
      float w = r0 * Wpwl[(0 * M_ + m0 + m) * F_ + f] + r1 * Wpwl[(1 * M_ + m0 + m) * F_ + f] +
                r2 * Wpwl[(2 * M_ + m0 + m) * F_ + f] + r3 * Wpwl[(3 * M_ + m0 + m) * F_ + f];
      float s3 = g3[f] * rsqrtf(v3[f] + EPS);
      tile2[f][m] = f2bf(w * s3);
    }
    __syncthreads();
    u16* dst = Wk2_t + (size_t)b * F_ * M_ + m0;
#pragma unroll
    for (int k = 0; k < 3; ++k) {
      int ch = t + 256 * k;
      int f = ch / 8, off = (ch % 8) * 8;
      *(short8*)&dst[(size_t)f * M_ + off] = *(const short8*)&tile2[f][off];
    }
  }
}

// ---------------- expand GEMM -> blocked h1 [b][oct][p][8]
__global__ __launch_bounds__(256) void k_expand(
    const u16* __restrict__ xbf, const u16* __restrict__ Wk_t,
    const float* __restrict__ bias1p, u16* __restrict__ h1b) {
  __shared__ __align__(16) u16 As[64][104];
  __shared__ __align__(16) u16 Bs[64][104];
  int pt = blockIdx.x, b = blockIdx.y;
  int p0 = pt * 64;
  int t = threadIdx.x;
  const u16* A = xbf + ((size_t)b * P_ + p0) * C_;
#pragma unroll
  for (int j = 0; j < 3; ++j) {
    int ch = t + 256 * j;
    int r = ch / 12, o = (ch % 12) * 8;
    *(short8*)&As[r][o] = *(const short8*)&A[(size_t)r * C_ + o];
  }
  const u16* Bt = Wk_t + (size_t)b * M_ * C_;
  u16* outb = h1b + (size_t)b * 48 * P_ * 8;
  int lane = t & 63, w = t >> 6;
  int rA = w * 16 + (lane & 15);
  int k0 = (lane >> 4) * 8;
  __syncthreads();
  for (int nt = 0; nt < 6; ++nt) {
    if (nt) __syncthreads();
#pragma unroll
    for (int j = 0; j < 3; ++j) {
      int ch = t + 256 * j;
      int r = ch / 12, o = (ch % 12) * 8;
      *(short8*)&Bs[r][o] = *(const short8*)&Bt[((size_t)(nt * 64 + r)) * C_ + o];
    }
    __syncthreads();
    f32x4 acc[4] = {};
#pragma unroll
    for (int kc = 0; kc < 3; ++kc) {
      bf16x8 a = *(const bf16x8*)&As[rA][kc * 32 + k0];
#pragma unroll
      for (int ct = 0; ct < 4; ++ct) {
        bf16x8 bb = *(const bf16x8*)&Bs[ct * 16 + (lane & 15)][kc * 32 + k0];
        acc[ct] = __builtin_amdgcn_mfma_f32_16x16x32_bf16(a, bb, acc[ct], 0, 0, 0);
      }
    }
    int rowb = p0 + w * 16 + (lane >> 4) * 4;
#pragma unroll
    for (int ct = 0; ct < 4; ++ct) {
      int m = nt * 64 + ct * 16 + (lane & 15);
      int oct = m >> 3, q = m & 7;
      float bias = bias1p[b * M_ + m];
#pragma unroll
      for (int i = 0; i < 4; ++i) {
        float v = fmaxf(acc[ct][i] + bias, 0.f);
        outb[((size_t)oct * P_ + rowb + i) * 8 + q] = f2bf(v);
      }
    }
  }
}

// ---------------- depthwise 3x3 + BN2 + relu; blocked layout in/out
// block = one (b, oct): stage whole 56x56x8ch image slice in LDS w/ zero halo
__global__ __launch_bounds__(512) void k_dw(
    const u16* __restrict__ h1b, const float* __restrict__ Wdwf_t,
    u16* __restrict__ h2b) {
  int oct = blockIdx.x, b = blockIdx.y;
  int t = threadIdx.x;
  __shared__ uint4 tile[58 * 58];

  int wbase = __builtin_amdgcn_readfirstlane((b * 48 + oct) * 80);
  const float* wo = Wdwf_t + wbase;
  f32x2 w2[40];
#pragma unroll
  for (int i = 0; i < 40; ++i) w2[i] = *(const f32x2*)&wo[i * 2];

  const uint4* in = (const uint4*)(h1b + ((size_t)b * 48 + oct) * P_ * 8);
  uint4* outb = (uint4*)(h2b + ((size_t)b * 48 + oct) * P_ * 8);

  // zero halo ring
  uint4 z = {0u, 0u, 0u, 0u};
  if (t < 58) { tile[t] = z; tile[57 * 58 + t] = z; }
  else if (t < 114) { int s = t - 58; tile[(s + 1) * 58] = z; tile[(s + 1) * 58 + 57] = z; }
  // stage interior (contiguous 49KB stream)
  for (int j = t; j < P_; j += 512) {
    int yy = j / 56, xx = j % 56;
    tile[(yy + 1) * 58 + xx + 1] = in[j];
  }
  __syncthreads();

  for (int i = t; i < P_; i += 512) {
    int y = i / 56, x = i % 56;
    f32x2 acc[4] = {w2[36], w2[37], w2[38], w2[39]};
#pragma unroll
    for (int dy = 0; dy < 3; ++dy) {
#pragma unroll
      for (int dx = 0; dx < 3; ++dx) {
        uint4 u = tile[(y + dy) * 58 + (x + dx)];
        int tap = dy * 3 + dx;
        acc[0] += bfpair(u.x) * w2[tap * 4 + 0];
        acc[1] += bfpair(u.y) * w2[tap * 4 + 1];
        acc[2] += bfpair(u.z) * w2[tap * 4 + 2];
        acc[3] += bfpair(u.w) * w2[tap * 4 + 3];
      }
    }
    unsigned o[4];
#pragma unroll
    for (int j = 0; j < 4; ++j) {
      float lo = fmaxf(acc[j].x, 0.f), hi = fmaxf(acc[j].y, 0.f);
      asm("v_cvt_pk_bf16_f32 %0, %1, %2" : "=v"(o[j]) : "v"(lo), "v"(hi));
    }
    uint4 st = {o[0], o[1], o[2], o[3]};
    outb[i] = st;
  }
}

// ---------------- project GEMM + bias + BN3(folded) + residual(bf16), fp32 out
__global__ __launch_bounds__(256) void k_proj(
    const u16* __restrict__ h2b, const u16* __restrict__ Wk2_t,
    const float* __restrict__ bias3p, const u16* __restrict__ xbf,
    float* __restrict__ outp) {
  __shared__ __align__(16) u16 As[64][104];
  __shared__ __align__(16) u16 Bs[96][104];
  int pt = blockIdx.x, b = blockIdx.y;
  int p0 = pt * 64;
  int t = threadIdx.x;
  const u16* h2base = h2b + (size_t)b * 48 * P_ * 8;
  const u16* Bt = Wk2_t + (size_t)b * F_ * M_;
  int lane = t & 63, w = t >> 6;
  int rA = w * 16 + (lane & 15);
  int k0 = (lane >> 4) * 8;
  f32x4 acc[6] = {};
  for (int kc = 0; kc < 4; ++kc) {
    if (kc) __syncthreads();
    // A-tile from blocked h2: k-chunk kc covers octs kc*12 .. kc*12+11
#pragma unroll
    for (int j = 0; j < 3; ++j) {
      int ch = t + 256 * j;
      int r = ch / 12, ol = ch % 12;
      *(short8*)&As[r][ol * 8] =
          *(const short8*)&h2base[((size_t)(kc * 12 + ol) * P_ + p0 + r) * 8];
    }
#pragma unroll
    for (int j = 0; j < 5; ++j) {
      int ch = t + 256 * j;
      if (ch < 96 * 12) {
        int r = ch / 12, o = (ch % 12) * 8;
        *(short8*)&Bs[r][o] = *(const short8*)&Bt[(size_t)r * M_ + kc * 96 + o];
      }
    }
    __syncthreads();
#pragma unroll
    for (int ks = 0; ks < 3; ++ks) {
      bf16x8 a = *(const bf16x8*)&As[rA][ks * 32 + k0];
#pragma unroll
      for (int ct = 0; ct < 6; ++ct) {
        bf16x8 bb = *(const bf16x8*)&Bs[ct * 16 + (lane & 15)][ks * 32 + k0];
        acc[ct] = __builtin_amdgcn_mfma_f32_16x16x32_bf16(a, bb, acc[ct], 0, 0, 0);
      }
    }
  }
  const u16* xr = xbf + (size_t)b * P_ * C_;
  float* op = outp + (size_t)b * P_ * F_;
  int rowb = p0 + w * 16 + (lane >> 4) * 4;
#pragma unroll
  for (int ct = 0; ct < 6; ++ct) {
    int f = ct * 16 + (lane & 15);
    float bias = bias3p[b * F_ + f];
#pragma unroll
    for (int i = 0; i < 4; ++i) {
      size_t idx = (size_t)(rowb + i) * F_ + f;
      op[idx] = acc[ct][i] + bias + bf2f(xr[idx]);
    }
  }
}

extern "C" void kernel_launch(void* const* d_in, const int* in_sizes, int n_in,
                              void* d_out, int out_size, void* d_ws, size_t ws_size,
                              hipStream_t stream) {
  (void)in_sizes; (void)n_in; (void)out_size; (void)ws_size;
  const float* x    = (const float*)d_in[0];
  const float* Wr   = (const float*)d_in[1];
  const float* br   = (const float*)d_in[2];
  const float* Wpw  = (const float*)d_in[3];
  const float* bpw  = (const float*)d_in[4];
  const float* Wdw  = (const float*)d_in[5];
  const float* bdw  = (const float*)d_in[6];
  const float* Wpwl = (const float*)d_in[7];
  const float* bpwl = (const float*)d_in[8];
  const float* g1 = (const float*)d_in[9];
  const float* b1 = (const float*)d_in[10];
  const float* m1 = (const float*)d_in[11];
  const float* v1 = (const float*)d_in[12];
  const float* g2 = (const float*)d_in[13];
  const float* b2 = (const float*)d_in[14];
  const float* m2 = (const float*)d_in[15];
  const float* v2 = (const float*)d_in[16];
  const float* g3 = (const float*)d_in[17];
  const float* b3 = (const float*)d_in[18];
  const float* m3 = (const float*)d_in[19];
  const float* v3 = (const float*)d_in[20];
  float* out = (float*)d_out;

  char* p = (char*)d_ws;
  auto alloc = [&](size_t bytes) {
    char* r = p;
    p += (bytes + 255) & ~(size_t)255;
    return r;
  };
  float* rw      = (float*)alloc((size_t)B_ * E_ * 4);
  float* partial = (float*)alloc((size_t)B_ * 64 * C_ * 4);
  u16*   xbf     = (u16*)  alloc((size_t)B_ * P_ * C_ * 2);
  u16*   Wk_t    = (u16*)  alloc((size_t)B_ * M_ * C_ * 2);
  float* bias1p  = (float*)alloc((size_t)B_ * M_ * 4);
  float* Wdwf_t  = (float*)alloc((size_t)B_ * 48 * 80 * 4);
  u16*   Wk2_t   = (u16*)  alloc((size_t)B_ * F_ * M_ * 2);
  float* bias3p  = (float*)alloc((size_t)B_ * F_ * 4);
  u16*   h1b     = (u16*)  alloc((size_t)B_ * P_ * M_ * 2);
  u16*   h2b     = (u16*)  alloc((size_t)B_ * P_ * M_ * 2);

  k_pool_convert<<<dim3(64, B_), 256, 0, stream>>>(x, partial, xbf);
  k_routing2<<<B_, 128, 0, stream>>>(partial, Wr, br, rw);
  k_mkall<<<dim3(B_, 13), 256, 0, stream>>>(Wpw, bpw, Wdw, bdw, Wpwl, bpwl, rw,
                                            g1, b1, m1, v1, g2, b2, m2, v2,
                                            g3, b3, m3, v3,
                                            Wk_t, bias1p, Wdwf_t, Wk2_t, bias3p);
  k_expand<<<dim3(49, B_), 256, 0, stream>>>(xbf, Wk_t, bias1p, h1b);
  k_dw<<<dim3(48, B_), 512, 0, stream>>>(h1b, Wdwf_t, h2b);
  k_proj<<<dim3(49, B_), 256, 0, stream>>>(h2b, Wk2_t, bias3p, xbf, out);
}